// Round 2
// baseline (978.526 us; speedup 1.0000x reference)
//
#include <hip/hip_runtime.h>
#include <hip/hip_bf16.h>

#define N_NODES   50000
#define EDGES     1600000
#define D         128
#define K_INC     2000
#define K_TOT     2128   // 2000 (inc) + 128 (curr_h)
#define K_PAD     2176   // padded to multiple of 64 (34 * 64)
#define KTILES    34
#define LN_EPS    1e-5f

typedef float f32x4 __attribute__((ext_vector_type(4)));
typedef short short8 __attribute__((ext_vector_type(8)));   // 8 bf16 lanes (MFMA operand)
typedef ushort ushort8v __attribute__((ext_vector_type(8)));

__device__ __forceinline__ ushort f2bf(float x) {
    return __hip_bfloat16_raw(__float2bfloat16(x)).x;
}
__device__ __forceinline__ float bf_lo(uint v) { return __uint_as_float(v << 16); }
__device__ __forceinline__ float bf_hi(uint v) { return __uint_as_float(v & 0xffff0000u); }

// async global->LDS, 16B per lane, LDS dest = wave-uniform base + lane*16
#define GLOAD_LDS16(gp, lp) \
    __builtin_amdgcn_global_load_lds((const __attribute__((address_space(1))) void*)(gp), \
                                     (__attribute__((address_space(3))) void*)(lp), 16, 0, 0)

// ---------------- index-width probe: flag=1 if src looks like raw int64 ----------------
__global__ void probe_kernel(const int* __restrict__ src, int* __restrict__ flag) {
    __shared__ int any_nonzero;
    if (threadIdx.x == 0) any_nonzero = 0;
    __syncthreads();
    int v = src[threadIdx.x * 2 + 1];   // odd words all-zero iff little-endian int64, vals < 2^31
    if (v != 0) any_nonzero = 1;
    __syncthreads();
    if (threadIdx.x == 0) flag[0] = any_nonzero ? 0 : 1;
}

// ---------------- zero fill ----------------
__global__ void zero_kernel(int* __restrict__ p, int n) {
    int i = blockIdx.x * 256 + threadIdx.x;
    if (i < n) p[i] = 0;
}

// ---------------- in-degree histogram (dst only; out_deg folded into fill) ----------------
// 2 edges per thread, full-cacheline int4/int2 loads on the index array.
__global__ void deg_kernel(const int* __restrict__ dst, const int* __restrict__ flag,
                           int* __restrict__ in_cnt) {
    int t = blockIdx.x * 256 + threadIdx.x;
    int e0 = t * 2;
    if (e0 >= EDGES) return;                 // EDGES even -> e0+1 also valid
    int d0, d1;
    if (flag[0]) {                           // int64 indices
        int4 v = *(const int4*)(dst + (size_t)e0 * 2);
        d0 = v.x; d1 = v.z;
    } else {                                 // int32 indices
        int2 v = *(const int2*)(dst + e0);
        d0 = v.x; d1 = v.y;
    }
    atomicAdd(&in_cnt[d0], 1);
    atomicAdd(&in_cnt[d1], 1);
}

// ---------------- one-block chunked exclusive scan over N ----------------
__global__ __launch_bounds__(1024) void scan_kernel(const int* __restrict__ cnt,
                                                    int* __restrict__ row_start) {
    __shared__ int buf[1024];
    int t = threadIdx.x;
    const int N = N_NODES;
    int chunk = (N + 1023) / 1024;
    int lo = t * chunk, hi = min(lo + chunk, N);
    int s = 0;
    for (int i = lo; i < hi; ++i) s += cnt[i];
    buf[t] = s;
    __syncthreads();
    for (int off = 1; off < 1024; off <<= 1) {
        int v = (t >= off) ? buf[t - off] : 0;
        __syncthreads();
        buf[t] += v;
        __syncthreads();
    }
    int run = (t > 0) ? buf[t - 1] : 0;
    for (int i = lo; i < hi; ++i) { row_start[i] = run; run += cnt[i]; }
    if (t == 1023) row_start[N] = buf[1023];
}

// ---------------- CSR scatter (dst-sorted src list) + out-degree ----------------
// 2 edges per thread, int4/int2 index loads.
__global__ void fill_kernel(const int* __restrict__ src, const int* __restrict__ dst,
                            const int* __restrict__ flag,
                            const int* __restrict__ row_start, int* __restrict__ cursor,
                            int* __restrict__ out_deg, int* __restrict__ csr_src) {
    int t = blockIdx.x * 256 + threadIdx.x;
    int e0 = t * 2;
    if (e0 >= EDGES) return;
    int s0, s1, d0, d1;
    if (flag[0]) {
        int4 vs = *(const int4*)(src + (size_t)e0 * 2);
        int4 vd = *(const int4*)(dst + (size_t)e0 * 2);
        s0 = vs.x; s1 = vs.z; d0 = vd.x; d1 = vd.z;
    } else {
        int2 vs = *(const int2*)(src + e0);
        int2 vd = *(const int2*)(dst + e0);
        s0 = vs.x; s1 = vs.y; d0 = vd.x; d1 = vd.y;
    }
    atomicAdd(&out_deg[s0], 1);
    int p0 = atomicAdd(&cursor[d0], 1);
    csr_src[row_start[d0] + p0] = s0;
    atomicAdd(&out_deg[s1], 1);
    int p1 = atomicAdd(&cursor[d1], 1);
    csr_src[row_start[d1] + p1] = s1;
}

// ---------------- PbT[n][k] (bf16): k<K_INC -> (next_h @ (W_fus .* topDown_w))^T;
// ---------------- K_INC..K_TOT -> (W_conv .* conv_w)^T; rest zero ----------------
#define PKB 16
__global__ __launch_bounds__(128) void p_kernel(
    const float* __restrict__ next_h, const float* __restrict__ W_fus,
    const float* __restrict__ topDown_w, const float* __restrict__ W_conv,
    const float* __restrict__ conv_w, ushort* __restrict__ PbT) {
    int n = threadIdx.x;
    int k0 = blockIdx.x * PKB;
    if (k0 < K_INC) {
        float acc[PKB];
#pragma unroll
        for (int t = 0; t < PKB; ++t) acc[t] = 0.f;
        for (int j = 0; j < D; ++j) {
            float w = W_fus[(size_t)j * D + n];
#pragma unroll
            for (int t = 0; t < PKB; ++t)
                acc[t] += next_h[(size_t)(k0 + t) * D + j] * w;   // uniform addr -> s_load
        }
        float tw = topDown_w[n];
#pragma unroll
        for (int t = 0; t < PKB; ++t)
            PbT[(size_t)n * K_PAD + k0 + t] = f2bf(acc[t] * tw);
    } else if (k0 < K_TOT) {
        float cw = conv_w[n];
#pragma unroll
        for (int t = 0; t < PKB; ++t)
            PbT[(size_t)n * K_PAD + k0 + t] = f2bf(W_conv[(size_t)(k0 + t - K_INC) * D + n] * cw);
    } else {
#pragma unroll
        for (int t = 0; t < PKB; ++t)
            PbT[(size_t)n * K_PAD + k0 + t] = 0;
    }
}

// ---------------- big GEMM: Zs(bf16) = ([inc | curr_h] @ PbT^T) * norm_out ----------------
// tile 64x128, BK=64, 256 threads (4 waves as 2x2 of 32x64 wave-tiles).
// Double-buffered, ONE barrier per K-tile: issue t+1 stage (A->regs, B->global_load_lds)
// before computing tile t. B LDS is linear (gload_lds requirement); bank conflicts fixed
// by both-sides XOR swizzle: pre-swizzled GLOBAL source + same XOR on ds_read address.
__global__ __launch_bounds__(256, 3) void gemm_kernel(
    const float* __restrict__ inc, const float* __restrict__ curr_h,
    const ushort* __restrict__ PbT, const int* __restrict__ out_deg,
    ushort* __restrict__ Zs) {
    __shared__ __align__(16) ushort As[2][64][72];      // padded [m][k] bf16 (reg-staged)
    __shared__ __align__(16) ushort Bs[2][128 * 64];    // linear [n][k] bf16 (gload_lds, swizzled)
    const int N = N_NODES;
    int tid = threadIdx.x;
    int wave = tid >> 6, lane = tid & 63;
    int wm = wave >> 1, wn = wave & 1;
    int r = lane & 15, q = lane >> 4;
    int rowBase = blockIdx.x * 64;

    f32x4 acc[2][4] = {};
    float4 aReg[2][2];

    auto stage_issue = [&](int kt, int nb) {
        int k0 = kt * 64;
        // A: 64 rows x 64 f32; each thread loads 8 consecutive f32 (2 x float4), 2 units
#pragma unroll
        for (int it = 0; it < 2; ++it) {
            int u = tid + it * 256;
            int arow = u >> 3, c8 = u & 7;
            int gk = k0 + c8 * 8;                       // K_INC, K_TOT are multiples of 8
            int grow = rowBase + arow; if (grow >= N) grow = N - 1;
            if (gk < K_INC) {
                const float4* p4 = (const float4*)(inc + (size_t)grow * K_INC + gk);
                aReg[it][0] = p4[0]; aReg[it][1] = p4[1];
            } else if (gk < K_TOT) {
                const float4* p4 = (const float4*)(curr_h + (size_t)grow * D + (gk - K_INC));
                aReg[it][0] = p4[0]; aReg[it][1] = p4[1];
            } else {
                aReg[it][0] = make_float4(0.f, 0.f, 0.f, 0.f);
                aReg[it][1] = make_float4(0.f, 0.f, 0.f, 0.f);
            }
        }
        // B: 128 rows x 64 bf16 = 16KB -> 16 wave-issues of 1KB. Linear LDS dest;
        // global source column pre-swizzled so swizzled ds_read reads it back straight.
#pragma unroll
        for (int it = 0; it < 4; ++it) {
            int chunk = tid + it * 256;                 // 0..1023, 16B each
            int n = chunk >> 3;                         // B row 0..127
            int c16 = (chunk & 7) << 4;                 // byte col within 128B row
            int gb = c16 ^ ((n & 7) << 4);              // inverse-swizzle the SOURCE
            const char* gp = (const char*)PbT + (size_t)n * (K_PAD * 2) + (size_t)(k0 * 2) + gb;
            char* lp = (char*)(&Bs[nb][0]) + it * 4096 + wave * 1024;  // wave-uniform base
            GLOAD_LDS16(gp, lp);
        }
    };
    auto stage_write = [&](int nb) {
#pragma unroll
        for (int it = 0; it < 2; ++it) {
            int u = tid + it * 256;
            int arow = u >> 3, c8 = u & 7;
            const float* f = (const float*)&aReg[it][0];
            ushort8v hv;
#pragma unroll
            for (int j = 0; j < 8; ++j) hv[j] = f2bf(f[j]);
            *(ushort8v*)&As[nb][arow][c8 * 8] = hv;     // b128, balanced banks (pad 72)
        }
    };

    // prologue: stage tile 0 into buf 0
    stage_issue(0, 0);
    stage_write(0);
    __syncthreads();

    int cur = 0;
    for (int kt = 0; kt < KTILES; ++kt) {
        int nb = cur ^ 1;
        if (kt + 1 < KTILES) stage_issue(kt + 1, nb);   // loads in flight under MFMA
#pragma unroll
        for (int kk = 0; kk < 2; ++kk) {
            short8 af[2], bfr[4];
#pragma unroll
            for (int mi = 0; mi < 2; ++mi)
                af[mi] = *(const short8*)&As[cur][wm * 32 + mi * 16 + r][kk * 32 + q * 8];
#pragma unroll
            for (int ni = 0; ni < 4; ++ni) {
                int brow = wn * 64 + ni * 16 + r;
                int bcol = (kk * 64 + q * 16) ^ ((r & 7) << 4);   // same XOR as source
                bfr[ni] = *(const short8*)((const char*)&Bs[cur][0] + brow * 128 + bcol);
            }
#pragma unroll
            for (int mi = 0; mi < 2; ++mi)
#pragma unroll
                for (int ni = 0; ni < 4; ++ni)
                    acc[mi][ni] = __builtin_amdgcn_mfma_f32_16x16x32_bf16(af[mi], bfr[ni], acc[mi][ni], 0, 0, 0);
        }
        if (kt + 1 < KTILES) stage_write(nb);           // vmcnt wait lands here, post-MFMA
        __syncthreads();                                // single barrier per K-tile
        cur = nb;
    }

#pragma unroll
    for (int mi = 0; mi < 2; ++mi) {
#pragma unroll
        for (int j = 0; j < 4; ++j) {
            int grow = rowBase + wm * 32 + mi * 16 + q * 4 + j;   // C/D: row = (lane>>4)*4 + reg [m89]
            if (grow < N) {
                float no = rsqrtf((float)(out_deg[grow] + 1));    // +1 self-loop
#pragma unroll
                for (int ni = 0; ni < 4; ++ni) {
                    int col = wn * 64 + ni * 16 + r;              // C/D: col = lane&15 [m89]
                    Zs[(size_t)grow * D + col] = f2bf(acc[mi][ni][j] * no);
                }
            }
        }
    }
}

// ---------------- fused aggregation + norm_in + bias + LayerNorm + ReLU ----------------
// 16 lanes per node (lane owns 8 channels = one uint4 of the 256B Zs row), 4 nodes/wave,
// 16 nodes/block. One wave-load now covers 4 edges (1024B/inst vs 256B/inst before).
// N_NODES = 50000 = 16 * 3125, so no tail handling needed.
__global__ __launch_bounds__(256) void agg_ln_kernel(
    const ushort* __restrict__ Zs, const int* __restrict__ row_start,
    const int* __restrict__ csr_src,
    const float* __restrict__ b_conv, const float* __restrict__ b_fus,
    const float* __restrict__ conv_w, const float* __restrict__ topDown_w,
    const float* __restrict__ gamma, const float* __restrict__ beta,
    float* __restrict__ out) {
    int tid = threadIdx.x;
    int wid = tid >> 6, lane = tid & 63;
    int sl = lane & 15;                       // sub-lane within node group
    int g = lane >> 4;                        // node group within wave
    int node = blockIdx.x * 16 + wid * 4 + g;
    int c0 = sl * 8;                          // first of 8 owned channels

    float a[8];
    {   // self-loop row
        uint4 v = *(const uint4*)(Zs + (size_t)node * D + c0);
        a[0] = bf_lo(v.x); a[1] = bf_hi(v.x);
        a[2] = bf_lo(v.y); a[3] = bf_hi(v.y);
        a[4] = bf_lo(v.z); a[5] = bf_hi(v.z);
        a[6] = bf_lo(v.w); a[7] = bf_hi(v.w);
    }

    int beg = row_start[node], end = row_start[node + 1];
    int deg = end - beg;
    // wave-max degree -> uniform outer loop
    int m = max(deg, __shfl_xor(deg, 16));
    m = max(m, __shfl_xor(m, 32));
    int srcbase = lane & 48;                  // first lane of this node's group

    for (int base = 0; base < m; base += 16) {
        int idx = 0;
        if (base + sl < deg) idx = csr_src[beg + base + sl];  // 16 coalesced ints / group
        int cnt = deg - base;                 // group-uniform remaining count
        if (cnt >= 16) {
            // full chunk: no predication
#pragma unroll
            for (int i = 0; i < 16; i += 4) {
                int s0 = __shfl(idx, srcbase + i);
                int s1 = __shfl(idx, srcbase + i + 1);
                int s2 = __shfl(idx, srcbase + i + 2);
                int s3 = __shfl(idx, srcbase + i + 3);
                uint4 v0 = *(const uint4*)(Zs + (size_t)s0 * D + c0);
                uint4 v1 = *(const uint4*)(Zs + (size_t)s1 * D + c0);
                uint4 v2 = *(const uint4*)(Zs + (size_t)s2 * D + c0);
                uint4 v3 = *(const uint4*)(Zs + (size_t)s3 * D + c0);
                a[0] += bf_lo(v0.x) + bf_lo(v1.x) + bf_lo(v2.x) + bf_lo(v3.x);
                a[1] += bf_hi(v0.x) + bf_hi(v1.x) + bf_hi(v2.x) + bf_hi(v3.x);
                a[2] += bf_lo(v0.y) + bf_lo(v1.y) + bf_lo(v2.y) + bf_lo(v3.y);
                a[3] += bf_hi(v0.y) + bf_hi(v1.y) + bf_hi(v2.y) + bf_hi(v3.y);
                a[4] += bf_lo(v0.z) + bf_lo(v1.z) + bf_lo(v2.z) + bf_lo(v3.z);
                a[5] += bf_hi(v0.z) + bf_hi(v1.z) + bf_hi(v2.z) + bf_hi(v3.z);
                a[6] += bf_lo(v0.w) + bf_lo(v1.w) + bf_lo(v2.w) + bf_lo(v3.w);
                a[7] += bf_hi(v0.w) + bf_hi(v1.w) + bf_hi(v2.w) + bf_hi(v3.w);
            }
        } else if (cnt > 0) {
            for (int i = 0; i < cnt; ++i) {
                int s0 = __shfl(idx, srcbase + i);
                uint4 v0 = *(const uint4*)(Zs + (size_t)s0 * D + c0);
                a[0] += bf_lo(v0.x); a[1] += bf_hi(v0.x);
                a[2] += bf_lo(v0.y); a[3] += bf_hi(v0.y);
                a[4] += bf_lo(v0.z); a[5] += bf_hi(v0.z);
                a[6] += bf_lo(v0.w); a[7] += bf_hi(v0.w);
            }
        }
    }

    float nin = rsqrtf((float)(deg + 1));
    float4 bc0 = *(const float4*)(b_conv + c0),   bc1 = *(const float4*)(b_conv + c0 + 4);
    float4 cw0 = *(const float4*)(conv_w + c0),   cw1 = *(const float4*)(conv_w + c0 + 4);
    float4 bf0 = *(const float4*)(b_fus + c0),    bf1 = *(const float4*)(b_fus + c0 + 4);
    float4 tw0 = *(const float4*)(topDown_w + c0),tw1 = *(const float4*)(topDown_w + c0 + 4);
    float bias[8] = {
        bc0.x * cw0.x + bf0.x * tw0.x, bc0.y * cw0.y + bf0.y * tw0.y,
        bc0.z * cw0.z + bf0.z * tw0.z, bc0.w * cw0.w + bf0.w * tw0.w,
        bc1.x * cw1.x + bf1.x * tw1.x, bc1.y * cw1.y + bf1.y * tw1.y,
        bc1.z * cw1.z + bf1.z * tw1.z, bc1.w * cw1.w + bf1.w * tw1.w };
    float y[8];
    float s1v = 0.f, s2v = 0.f;
#pragma unroll
    for (int j = 0; j < 8; ++j) {
        y[j] = a[j] * nin + bias[j];
        s1v += y[j]; s2v += y[j] * y[j];
    }
#pragma unroll
    for (int off = 1; off < 16; off <<= 1) {   // reduce within the 16-lane group
        s1v += __shfl_xor(s1v, off);
        s2v += __shfl_xor(s2v, off);
    }
    float mu = s1v * (1.f / D);
    float var = s2v * (1.f / D) - mu * mu;
    float rstd = rsqrtf(var + LN_EPS);
    float4 ga0 = *(const float4*)(gamma + c0), ga1 = *(const float4*)(gamma + c0 + 4);
    float4 be0 = *(const float4*)(beta + c0),  be1 = *(const float4*)(beta + c0 + 4);
    float gam[8] = { ga0.x, ga0.y, ga0.z, ga0.w, ga1.x, ga1.y, ga1.z, ga1.w };
    float bet[8] = { be0.x, be0.y, be0.z, be0.w, be1.x, be1.y, be1.z, be1.w };
    float4 o0, o1;
    float r;
    r = (y[0] - mu) * rstd * gam[0] + bet[0]; o0.x = fmaxf(r, 0.f);
    r = (y[1] - mu) * rstd * gam[1] + bet[1]; o0.y = fmaxf(r, 0.f);
    r = (y[2] - mu) * rstd * gam[2] + bet[2]; o0.z = fmaxf(r, 0.f);
    r = (y[3] - mu) * rstd * gam[3] + bet[3]; o0.w = fmaxf(r, 0.f);
    r = (y[4] - mu) * rstd * gam[4] + bet[4]; o1.x = fmaxf(r, 0.f);
    r = (y[5] - mu) * rstd * gam[5] + bet[5]; o1.y = fmaxf(r, 0.f);
    r = (y[6] - mu) * rstd * gam[6] + bet[6]; o1.z = fmaxf(r, 0.f);
    r = (y[7] - mu) * rstd * gam[7] + bet[7]; o1.w = fmaxf(r, 0.f);
    *(float4*)(out + (size_t)node * D + c0) = o0;
    *(float4*)(out + (size_t)node * D + c0 + 4) = o1;
}

extern "C" void kernel_launch(void* const* d_in, const int* in_sizes, int n_in,
                              void* d_out, int out_size, void* d_ws, size_t ws_size,
                              hipStream_t stream) {
    const float* curr_h    = (const float*)d_in[0];
    const float* next_h    = (const float*)d_in[1];
    const float* inc       = (const float*)d_in[2];
    const int*   src       = (const int*)d_in[3];
    const int*   dst       = (const int*)d_in[4];
    const float* W_conv    = (const float*)d_in[5];
    const float* b_conv    = (const float*)d_in[6];
    const float* W_fus     = (const float*)d_in[7];
    const float* b_fus     = (const float*)d_in[8];
    const float* conv_w    = (const float*)d_in[9];
    const float* topDown_w = (const float*)d_in[10];
    const float* ln_gamma  = (const float*)d_in[11];
    const float* ln_beta   = (const float*)d_in[12];

    const int N = N_NODES;
    const int E = EDGES;

    // ---- workspace carve ----
    char* p = (char*)d_ws;
    ushort* Zs = (ushort*)p;     p += (size_t)N * D * sizeof(ushort);   // 12.8 MB (bf16)
    ushort* PbT = (ushort*)p;    p += (size_t)D * K_PAD * 2;            // 557 KB
    int* out_deg   = (int*)p;    p += (size_t)N * 4;                    // contiguous: out_deg,in_cnt,cursor
    int* in_cnt    = (int*)p;    p += (size_t)N * 4;
    int* cursor    = (int*)p;    p += (size_t)N * 4;
    int* row_start = (int*)p;    p += (size_t)(N + 1) * 4;
    int* idx_flag  = (int*)p;    p += 256;
    int* csr_src   = (int*)p;    p += (size_t)E * 4;

    probe_kernel<<<1, 1024, 0, stream>>>(src, idx_flag);
    zero_kernel<<<(3 * N + 255) / 256, 256, 0, stream>>>(out_deg, 3 * N);
    deg_kernel<<<(E / 2 + 255) / 256, 256, 0, stream>>>(dst, idx_flag, in_cnt);
    scan_kernel<<<1, 1024, 0, stream>>>(in_cnt, row_start);
    fill_kernel<<<(E / 2 + 255) / 256, 256, 0, stream>>>(src, dst, idx_flag, row_start,
                                                         cursor, out_deg, csr_src);
    p_kernel<<<K_PAD / PKB, 128, 0, stream>>>(next_h, W_fus, topDown_w, W_conv, conv_w, PbT);
    gemm_kernel<<<(N + 63) / 64, 256, 0, stream>>>(inc, curr_h, PbT, out_deg, Zs);
    agg_ln_kernel<<<(N + 15) / 16, 256, 0, stream>>>(Zs, row_start, csr_src,
                                                     b_conv, b_fus, conv_w, topDown_w,
                                                     ln_gamma, ln_beta, (float*)d_out);
}

// Round 3
// 961.361 us; speedup vs baseline: 1.0179x; 1.0179x over previous
//
#include <hip/hip_runtime.h>
#include <hip/hip_bf16.h>

#define N_NODES   50000
#define EDGES     1600000
#define D         128
#define K_INC     2000
#define K_TOT     2128   // 2000 (inc) + 128 (curr_h)
#define K_PAD     2176   // padded to multiple of 64 (34 * 64)
#define KTILES    34
#define LN_EPS    1e-5f

typedef float f32x4 __attribute__((ext_vector_type(4)));
typedef short short8 __attribute__((ext_vector_type(8)));   // 8 bf16 lanes (MFMA operand)
typedef ushort ushort8v __attribute__((ext_vector_type(8)));

__device__ __forceinline__ ushort f2bf(float x) {
    return __hip_bfloat16_raw(__float2bfloat16(x)).x;
}
__device__ __forceinline__ float bf_lo(uint v) { return __uint_as_float(v << 16); }
__device__ __forceinline__ float bf_hi(uint v) { return __uint_as_float(v & 0xffff0000u); }

// async global->LDS, 16B per lane, LDS dest = wave-uniform base + lane*16
#define GLOAD_LDS16(gp, lp) \
    __builtin_amdgcn_global_load_lds((const __attribute__((address_space(1))) void*)(gp), \
                                     (__attribute__((address_space(3))) void*)(lp), 16, 0, 0)

// ---------------- index-width probe: flag=1 if src looks like raw int64 ----------------
__global__ void probe_kernel(const int* __restrict__ src, int* __restrict__ flag) {
    __shared__ int any_nonzero;
    if (threadIdx.x == 0) any_nonzero = 0;
    __syncthreads();
    int v = src[threadIdx.x * 2 + 1];   // odd words all-zero iff little-endian int64, vals < 2^31
    if (v != 0) any_nonzero = 1;
    __syncthreads();
    if (threadIdx.x == 0) flag[0] = any_nonzero ? 0 : 1;
}

// ---------------- zero fill ----------------
__global__ void zero_kernel(int* __restrict__ p, int n) {
    int i = blockIdx.x * 256 + threadIdx.x;
    if (i < n) p[i] = 0;
}

// ---------------- in-degree histogram (dst only; out_deg folded into fill) ----------------
// 2 edges per thread, full-cacheline int4/int2 loads on the index array.
__global__ void deg_kernel(const int* __restrict__ dst, const int* __restrict__ flag,
                           int* __restrict__ in_cnt) {
    int t = blockIdx.x * 256 + threadIdx.x;
    int e0 = t * 2;
    if (e0 >= EDGES) return;                 // EDGES even -> e0+1 also valid
    int d0, d1;
    if (flag[0]) {                           // int64 indices
        int4 v = *(const int4*)(dst + (size_t)e0 * 2);
        d0 = v.x; d1 = v.z;
    } else {                                 // int32 indices
        int2 v = *(const int2*)(dst + e0);
        d0 = v.x; d1 = v.y;
    }
    atomicAdd(&in_cnt[d0], 1);
    atomicAdd(&in_cnt[d1], 1);
}

// ---------------- one-block chunked exclusive scan over N ----------------
__global__ __launch_bounds__(1024) void scan_kernel(const int* __restrict__ cnt,
                                                    int* __restrict__ row_start) {
    __shared__ int buf[1024];
    int t = threadIdx.x;
    const int N = N_NODES;
    int chunk = (N + 1023) / 1024;
    int lo = t * chunk, hi = min(lo + chunk, N);
    int s = 0;
    for (int i = lo; i < hi; ++i) s += cnt[i];
    buf[t] = s;
    __syncthreads();
    for (int off = 1; off < 1024; off <<= 1) {
        int v = (t >= off) ? buf[t - off] : 0;
        __syncthreads();
        buf[t] += v;
        __syncthreads();
    }
    int run = (t > 0) ? buf[t - 1] : 0;
    for (int i = lo; i < hi; ++i) { row_start[i] = run; run += cnt[i]; }
    if (t == 1023) row_start[N] = buf[1023];
}

// ---------------- CSR scatter (dst-sorted src list) + out-degree ----------------
// 2 edges per thread, int4/int2 index loads.
__global__ void fill_kernel(const int* __restrict__ src, const int* __restrict__ dst,
                            const int* __restrict__ flag,
                            const int* __restrict__ row_start, int* __restrict__ cursor,
                            int* __restrict__ out_deg, int* __restrict__ csr_src) {
    int t = blockIdx.x * 256 + threadIdx.x;
    int e0 = t * 2;
    if (e0 >= EDGES) return;
    int s0, s1, d0, d1;
    if (flag[0]) {
        int4 vs = *(const int4*)(src + (size_t)e0 * 2);
        int4 vd = *(const int4*)(dst + (size_t)e0 * 2);
        s0 = vs.x; s1 = vs.z; d0 = vd.x; d1 = vd.z;
    } else {
        int2 vs = *(const int2*)(src + e0);
        int2 vd = *(const int2*)(dst + e0);
        s0 = vs.x; s1 = vs.y; d0 = vd.x; d1 = vd.y;
    }
    atomicAdd(&out_deg[s0], 1);
    int p0 = atomicAdd(&cursor[d0], 1);
    csr_src[row_start[d0] + p0] = s0;
    atomicAdd(&out_deg[s1], 1);
    int p1 = atomicAdd(&cursor[d1], 1);
    csr_src[row_start[d1] + p1] = s1;
}

// ---------------- PbT[n][k] (bf16): k<K_INC -> (next_h @ (W_fus .* topDown_w))^T;
// ---------------- K_INC..K_TOT -> (W_conv .* conv_w)^T; rest zero ----------------
#define PKB 16
__global__ __launch_bounds__(128) void p_kernel(
    const float* __restrict__ next_h, const float* __restrict__ W_fus,
    const float* __restrict__ topDown_w, const float* __restrict__ W_conv,
    const float* __restrict__ conv_w, ushort* __restrict__ PbT) {
    int n = threadIdx.x;
    int k0 = blockIdx.x * PKB;
    if (k0 < K_INC) {
        float acc[PKB];
#pragma unroll
        for (int t = 0; t < PKB; ++t) acc[t] = 0.f;
        for (int j = 0; j < D; ++j) {
            float w = W_fus[(size_t)j * D + n];
#pragma unroll
            for (int t = 0; t < PKB; ++t)
                acc[t] += next_h[(size_t)(k0 + t) * D + j] * w;   // uniform addr -> s_load
        }
        float tw = topDown_w[n];
#pragma unroll
        for (int t = 0; t < PKB; ++t)
            PbT[(size_t)n * K_PAD + k0 + t] = f2bf(acc[t] * tw);
    } else if (k0 < K_TOT) {
        float cw = conv_w[n];
#pragma unroll
        for (int t = 0; t < PKB; ++t)
            PbT[(size_t)n * K_PAD + k0 + t] = f2bf(W_conv[(size_t)(k0 + t - K_INC) * D + n] * cw);
    } else {
#pragma unroll
        for (int t = 0; t < PKB; ++t)
            PbT[(size_t)n * K_PAD + k0 + t] = 0;
    }
}

// ---------------- big GEMM: Zs(bf16) = ([inc | curr_h] @ PbT^T) * norm_out ----------------
// tile 64x128, BK=64, 256 threads (4 waves as 2x2 of 32x64 wave-tiles).
// Double-buffered, ONE barrier per K-tile: issue t+1 stage (A->regs, B->global_load_lds)
// before computing tile t. B LDS is linear (gload_lds requirement); bank conflicts fixed
// by both-sides XOR swizzle: pre-swizzled GLOBAL source + same XOR on ds_read address.
__global__ __launch_bounds__(256, 3) void gemm_kernel(
    const float* __restrict__ inc, const float* __restrict__ curr_h,
    const ushort* __restrict__ PbT, const int* __restrict__ out_deg,
    ushort* __restrict__ Zs) {
    __shared__ __align__(16) ushort As[2][64][72];      // padded [m][k] bf16 (reg-staged)
    __shared__ __align__(16) ushort Bs[2][128 * 64];    // linear [n][k] bf16 (gload_lds, swizzled)
    const int N = N_NODES;
    int tid = threadIdx.x;
    int wave = tid >> 6, lane = tid & 63;
    int wm = wave >> 1, wn = wave & 1;
    int r = lane & 15, q = lane >> 4;
    int rowBase = blockIdx.x * 64;

    f32x4 acc[2][4] = {};
    float4 aReg[2][2];

    auto stage_issue = [&](int kt, int nb) {
        int k0 = kt * 64;
        // A: 64 rows x 64 f32; each thread loads 8 consecutive f32 (2 x float4), 2 units
#pragma unroll
        for (int it = 0; it < 2; ++it) {
            int u = tid + it * 256;
            int arow = u >> 3, c8 = u & 7;
            int gk = k0 + c8 * 8;                       // K_INC, K_TOT are multiples of 8
            int grow = rowBase + arow; if (grow >= N) grow = N - 1;
            if (gk < K_INC) {
                const float4* p4 = (const float4*)(inc + (size_t)grow * K_INC + gk);
                aReg[it][0] = p4[0]; aReg[it][1] = p4[1];
            } else if (gk < K_TOT) {
                const float4* p4 = (const float4*)(curr_h + (size_t)grow * D + (gk - K_INC));
                aReg[it][0] = p4[0]; aReg[it][1] = p4[1];
            } else {
                aReg[it][0] = make_float4(0.f, 0.f, 0.f, 0.f);
                aReg[it][1] = make_float4(0.f, 0.f, 0.f, 0.f);
            }
        }
        // B: 128 rows x 64 bf16 = 16KB -> 16 wave-issues of 1KB. Linear LDS dest;
        // global source column pre-swizzled so swizzled ds_read reads it back straight.
#pragma unroll
        for (int it = 0; it < 4; ++it) {
            int chunk = tid + it * 256;                 // 0..1023, 16B each
            int n = chunk >> 3;                         // B row 0..127
            int c16 = (chunk & 7) << 4;                 // byte col within 128B row
            int gb = c16 ^ ((n & 7) << 4);              // inverse-swizzle the SOURCE
            const char* gp = (const char*)PbT + (size_t)n * (K_PAD * 2) + (size_t)(k0 * 2) + gb;
            char* lp = (char*)(&Bs[nb][0]) + it * 4096 + wave * 1024;  // wave-uniform base
            GLOAD_LDS16(gp, lp);
        }
    };
    auto stage_write = [&](int nb) {
#pragma unroll
        for (int it = 0; it < 2; ++it) {
            int u = tid + it * 256;
            int arow = u >> 3, c8 = u & 7;
            const float* f = (const float*)&aReg[it][0];
            ushort8v hv;
#pragma unroll
            for (int j = 0; j < 8; ++j) hv[j] = f2bf(f[j]);
            *(ushort8v*)&As[nb][arow][c8 * 8] = hv;     // b128, balanced banks (pad 72)
        }
    };

    // prologue: stage tile 0 into buf 0
    stage_issue(0, 0);
    stage_write(0);
    __syncthreads();

    int cur = 0;
    for (int kt = 0; kt < KTILES; ++kt) {
        int nb = cur ^ 1;
        if (kt + 1 < KTILES) stage_issue(kt + 1, nb);   // loads in flight under MFMA
#pragma unroll
        for (int kk = 0; kk < 2; ++kk) {
            short8 af[2], bfr[4];
#pragma unroll
            for (int mi = 0; mi < 2; ++mi)
                af[mi] = *(const short8*)&As[cur][wm * 32 + mi * 16 + r][kk * 32 + q * 8];
#pragma unroll
            for (int ni = 0; ni < 4; ++ni) {
                int brow = wn * 64 + ni * 16 + r;
                int bcol = (kk * 64 + q * 16) ^ ((r & 7) << 4);   // same XOR as source
                bfr[ni] = *(const short8*)((const char*)&Bs[cur][0] + brow * 128 + bcol);
            }
#pragma unroll
            for (int mi = 0; mi < 2; ++mi)
#pragma unroll
                for (int ni = 0; ni < 4; ++ni)
                    acc[mi][ni] = __builtin_amdgcn_mfma_f32_16x16x32_bf16(af[mi], bfr[ni], acc[mi][ni], 0, 0, 0);
        }
        if (kt + 1 < KTILES) stage_write(nb);           // vmcnt wait lands here, post-MFMA
        __syncthreads();                                // single barrier per K-tile
        cur = nb;
    }

#pragma unroll
    for (int mi = 0; mi < 2; ++mi) {
#pragma unroll
        for (int j = 0; j < 4; ++j) {
            int grow = rowBase + wm * 32 + mi * 16 + q * 4 + j;   // C/D: row = (lane>>4)*4 + reg [m89]
            if (grow < N) {
                float no = rsqrtf((float)(out_deg[grow] + 1));    // +1 self-loop
#pragma unroll
                for (int ni = 0; ni < 4; ++ni) {
                    int col = wn * 64 + ni * 16 + r;              // C/D: col = lane&15 [m89]
                    Zs[(size_t)grow * D + col] = f2bf(acc[mi][ni][j] * no);
                }
            }
        }
    }
}

// ---------------- fused aggregation + norm_in + bias + LayerNorm + ReLU ----------------
// 1 node per wave (no divergence), lane owns 4 channels (uint2 = 8B of the 256B row).
// Wave halves process alternating edges: one gather instruction covers 2 edges (512B).
// Halves merged with shfl_xor(32) at the end. 4 nodes per 256-thread block.
__global__ __launch_bounds__(256) void agg_ln_kernel(
    const ushort* __restrict__ Zs, const int* __restrict__ row_start,
    const int* __restrict__ csr_src,
    const float* __restrict__ b_conv, const float* __restrict__ b_fus,
    const float* __restrict__ conv_w, const float* __restrict__ topDown_w,
    const float* __restrict__ gamma, const float* __restrict__ beta,
    float* __restrict__ out) {
    int wid = threadIdx.x >> 6, lane = threadIdx.x & 63;
    int node = blockIdx.x * 4 + wid;
    if (node >= N_NODES) return;
    int half = lane >> 5;                 // 0: even edge of pair, 1: odd edge
    int c0 = (lane & 31) * 4;             // 4 owned channels

    float a0 = 0.f, a1 = 0.f, a2 = 0.f, a3 = 0.f;
    if (!half) {                          // self-loop row counted once (half 0 only)
        uint2 v = *(const uint2*)(Zs + (size_t)node * D + c0);
        a0 = bf_lo(v.x); a1 = bf_hi(v.x); a2 = bf_lo(v.y); a3 = bf_hi(v.y);
    }

    int beg = row_start[node], end = row_start[node + 1];
    int deg = end - beg;

    for (int base = 0; base < deg; base += 64) {
        int rem = deg - base;
        int cnt = rem < 64 ? rem : 64;    // wave-uniform
        int idx = 0;
        if (base + lane < deg) idx = csr_src[beg + base + lane];  // one 256B coalesced load
        int np = cnt >> 1;                // full pairs
        int t = 0;
        for (; t + 4 <= np; t += 4) {     // 8 edges per iteration, 4 insts of 512B
            int s0 = __shfl(idx, 2 * t + half);
            int s1 = __shfl(idx, 2 * t + 2 + half);
            int s2 = __shfl(idx, 2 * t + 4 + half);
            int s3 = __shfl(idx, 2 * t + 6 + half);
            uint2 v0 = *(const uint2*)(Zs + (size_t)s0 * D + c0);
            uint2 v1 = *(const uint2*)(Zs + (size_t)s1 * D + c0);
            uint2 v2 = *(const uint2*)(Zs + (size_t)s2 * D + c0);
            uint2 v3 = *(const uint2*)(Zs + (size_t)s3 * D + c0);
            a0 += bf_lo(v0.x) + bf_lo(v1.x) + bf_lo(v2.x) + bf_lo(v3.x);
            a1 += bf_hi(v0.x) + bf_hi(v1.x) + bf_hi(v2.x) + bf_hi(v3.x);
            a2 += bf_lo(v0.y) + bf_lo(v1.y) + bf_lo(v2.y) + bf_lo(v3.y);
            a3 += bf_hi(v0.y) + bf_hi(v1.y) + bf_hi(v2.y) + bf_hi(v3.y);
        }
        for (; t < np; ++t) {
            int s0 = __shfl(idx, 2 * t + half);
            uint2 v0 = *(const uint2*)(Zs + (size_t)s0 * D + c0);
            a0 += bf_lo(v0.x); a1 += bf_hi(v0.x);
            a2 += bf_lo(v0.y); a3 += bf_hi(v0.y);
        }
        if (cnt & 1) {                    // odd tail edge: half 0 only
            int s0 = __shfl(idx, cnt - 1);
            if (!half) {
                uint2 v0 = *(const uint2*)(Zs + (size_t)s0 * D + c0);
                a0 += bf_lo(v0.x); a1 += bf_hi(v0.x);
                a2 += bf_lo(v0.y); a3 += bf_hi(v0.y);
            }
        }
    }

    // merge halves: lane L and L^32 own the same 4 channels
    a0 += __shfl_xor(a0, 32);
    a1 += __shfl_xor(a1, 32);
    a2 += __shfl_xor(a2, 32);
    a3 += __shfl_xor(a3, 32);

    float nin = rsqrtf((float)(deg + 1));
    float4 bc = *(const float4*)(b_conv + c0);
    float4 cw = *(const float4*)(conv_w + c0);
    float4 bfv = *(const float4*)(b_fus + c0);
    float4 tw = *(const float4*)(topDown_w + c0);
    float y0 = a0 * nin + bc.x * cw.x + bfv.x * tw.x;
    float y1 = a1 * nin + bc.y * cw.y + bfv.y * tw.y;
    float y2 = a2 * nin + bc.z * cw.z + bfv.z * tw.z;
    float y3 = a3 * nin + bc.w * cw.w + bfv.w * tw.w;

    float s1v = y0 + y1 + y2 + y3;
    float s2v = y0 * y0 + y1 * y1 + y2 * y2 + y3 * y3;
#pragma unroll
    for (int off = 1; off < 32; off <<= 1) {   // lanes 0-31 cover all 128 channels
        s1v += __shfl_xor(s1v, off);
        s2v += __shfl_xor(s2v, off);
    }
    float mu = s1v * (1.f / D);
    float var = s2v * (1.f / D) - mu * mu;
    float rstd = rsqrtf(var + LN_EPS);
    if (!half) {                                // half 0 writes the row
        float4 ga = *(const float4*)(gamma + c0);
        float4 be = *(const float4*)(beta + c0);
        float4 o;
        float r;
        r = (y0 - mu) * rstd * ga.x + be.x; o.x = fmaxf(r, 0.f);
        r = (y1 - mu) * rstd * ga.y + be.y; o.y = fmaxf(r, 0.f);
        r = (y2 - mu) * rstd * ga.z + be.z; o.z = fmaxf(r, 0.f);
        r = (y3 - mu) * rstd * ga.w + be.w; o.w = fmaxf(r, 0.f);
        *(float4*)(out + (size_t)node * D + c0) = o;
    }
}

extern "C" void kernel_launch(void* const* d_in, const int* in_sizes, int n_in,
                              void* d_out, int out_size, void* d_ws, size_t ws_size,
                              hipStream_t stream) {
    const float* curr_h    = (const float*)d_in[0];
    const float* next_h    = (const float*)d_in[1];
    const float* inc       = (const float*)d_in[2];
    const int*   src       = (const int*)d_in[3];
    const int*   dst       = (const int*)d_in[4];
    const float* W_conv    = (const float*)d_in[5];
    const float* b_conv    = (const float*)d_in[6];
    const float* W_fus     = (const float*)d_in[7];
    const float* b_fus     = (const float*)d_in[8];
    const float* conv_w    = (const float*)d_in[9];
    const float* topDown_w = (const float*)d_in[10];
    const float* ln_gamma  = (const float*)d_in[11];
    const float* ln_beta   = (const float*)d_in[12];

    const int N = N_NODES;
    const int E = EDGES;

    // ---- workspace carve ----
    char* p = (char*)d_ws;
    ushort* Zs = (ushort*)p;     p += (size_t)N * D * sizeof(ushort);   // 12.8 MB (bf16)
    ushort* PbT = (ushort*)p;    p += (size_t)D * K_PAD * 2;            // 557 KB
    int* out_deg   = (int*)p;    p += (size_t)N * 4;                    // contiguous: out_deg,in_cnt,cursor
    int* in_cnt    = (int*)p;    p += (size_t)N * 4;
    int* cursor    = (int*)p;    p += (size_t)N * 4;
    int* row_start = (int*)p;    p += (size_t)(N + 1) * 4;
    int* idx_flag  = (int*)p;    p += 256;
    int* csr_src   = (int*)p;    p += (size_t)E * 4;

    probe_kernel<<<1, 1024, 0, stream>>>(src, idx_flag);
    zero_kernel<<<(3 * N + 255) / 256, 256, 0, stream>>>(out_deg, 3 * N);
    deg_kernel<<<(E / 2 + 255) / 256, 256, 0, stream>>>(dst, idx_flag, in_cnt);
    scan_kernel<<<1, 1024, 0, stream>>>(in_cnt, row_start);
    fill_kernel<<<(E / 2 + 255) / 256, 256, 0, stream>>>(src, dst, idx_flag, row_start,
                                                         cursor, out_deg, csr_src);
    p_kernel<<<K_PAD / PKB, 128, 0, stream>>>(next_h, W_fus, topDown_w, W_conv, conv_w, PbT);
    gemm_kernel<<<(N + 63) / 64, 256, 0, stream>>>(inc, curr_h, PbT, out_deg, Zs);
    agg_ln_kernel<<<(N + 3) / 4, 256, 0, stream>>>(Zs, row_start, csr_src,
                                                   b_conv, b_fus, conv_w, topDown_w,
                                                   ln_gamma, ln_beta, (float*)d_out);
}